// Round 8
// baseline (1083.671 us; speedup 1.0000x reference)
//
#include <hip/hip_runtime.h>

// Problem constants
constexpr int Bn  = 128;
constexpr int Tn  = 48000;
constexpr int NFn = 2999;   // fast frames
constexpr int NSn = 999;    // slow frames
constexpr int G3n = 192;    // 3*GH
constexpr int GHn = 64;

typedef float f2 __attribute__((ext_vector_type(2)));

// ---------------------------------------------------------------------------
// Kernel 1: GI[b, t, j] = b_ih[j] + sum_{k<96} x[b, t*48+k] * W_ih[j, k]
// (unchanged — known-good, no spills)
// ---------------------------------------------------------------------------
__global__ __launch_bounds__(192) void gi_kernel(const float* __restrict__ x,
                                                 const float* __restrict__ W_ih,
                                                 const float* __restrict__ b_ih,
                                                 float* __restrict__ GI) {
  __shared__ __align__(16) float WT[48 * 196];   // [k][j] padded stride 196
  __shared__ float xs[1584];                     // 31*48+96 samples
  const int tile = blockIdx.x;        // 0..31
  const int b    = blockIdx.y;        // 0..127
  const int t0   = tile * 32;
  const int nt   = min(32, NSn - t0); // 32 or 7 (last tile)
  const int tid  = threadIdx.x;

  const int span = (nt - 1) * 48 + 96;
  for (int i = tid; i < 1584; i += 192)
    xs[i] = (i < span) ? x[(size_t)b * Tn + t0 * 48 + i] : 0.0f;

  const int jq = tid % 48;   // j-quad index
  const int tg = tid / 48;   // t-group (0..3)
  const int j0 = jq * 4;

  float acc[8][4];
#pragma unroll
  for (int u = 0; u < 8; ++u)
#pragma unroll
    for (int jj = 0; jj < 4; ++jj) acc[u][jj] = b_ih[j0 + jj];

  for (int half = 0; half < 2; ++half) {
    __syncthreads();
    for (int e = tid; e < 192 * 48; e += 192) {
      int j = e / 48, k = e % 48;
      WT[k * 196 + j] = W_ih[j * 96 + half * 48 + k];
    }
    __syncthreads();
    for (int k = 0; k < 48; ++k) {
      float4 w = *(const float4*)&WT[k * 196 + j0];
#pragma unroll
      for (int u = 0; u < 8; ++u) {
        float xv = xs[(tg * 8 + u) * 48 + half * 48 + k];
        acc[u][0] = fmaf(xv, w.x, acc[u][0]);
        acc[u][1] = fmaf(xv, w.y, acc[u][1]);
        acc[u][2] = fmaf(xv, w.z, acc[u][2]);
        acc[u][3] = fmaf(xv, w.w, acc[u][3]);
      }
    }
  }

#pragma unroll
  for (int u = 0; u < 8; ++u) {
    int tl = tg * 8 + u;
    if (tl < nt) {
      float4 st = make_float4(acc[u][0], acc[u][1], acc[u][2], acc[u][3]);
      *(float4*)&GI[(size_t)(b * NSn + t0 + tl) * G3n + j0] = st;
    }
  }
}

// ---------------------------------------------------------------------------
// Kernel 2: GRU, one wave per batch element. Thread j owns gate rows
// (r_j, z_j, n_j) = 192 weight floats — pinned in the AGPR half of the
// unified gfx950 register file via the "a" inline-asm constraint.
// Rounds 3-7 evidence: the arch-VGPR allocation cannot be pushed past ~132
// from source (launch_bounds / waves_per_eu / num_vgpr all ignored), so
// weights never fit in VGPRs and get re-loaded/spilled every step (the
// ~1170 cyc/step invariant). AGPRs are a separate allocation: pinning the
// weights there drops arch-VGPR pressure to ~60 and makes them physically
// resident. CDNA VALU can source one AGPR operand per instruction (worst
// case the compiler inserts v_accvgpr_read copies — still no memory
// traffic). h broadcast via LDS float4 reads (same-address = conflict-free).
// ---------------------------------------------------------------------------
__device__ __forceinline__ float fsigmoid(float v) {
  return __fdividef(1.0f, 1.0f + __expf(-v));
}
__device__ __forceinline__ float ftanh_f(float v) {
  return 1.0f - __fdividef(2.0f, __expf(2.0f * v) + 1.0f);
}

__global__ __launch_bounds__(64, 1)
void gru_kernel(const float* __restrict__ GI,
                const float* __restrict__ W_hh,
                const float* __restrict__ b_hh,
                float* __restrict__ hs) {
  __shared__ __align__(16) float hbuf[64];
  const int b = blockIdx.x;
  const int j = threadIdx.x;

  f2 wr2[32], wz2[32], wn2[32];
  const f2* Wr = (const f2*)(W_hh + (size_t)j * 64);
  const f2* Wz = (const f2*)(W_hh + (size_t)(j + 64) * 64);
  const f2* Wn = (const f2*)(W_hh + (size_t)(j + 128) * 64);
#pragma unroll
  for (int q = 0; q < 32; ++q) { wr2[q] = Wr[q]; wz2[q] = Wz[q]; wn2[q] = Wn[q]; }
  // Pin every weight into the AGPR file: off the arch-VGPR budget, opaque
  // to the compiler => cannot be re-loaded from memory or spilled to scratch.
#pragma unroll
  for (int q = 0; q < 32; ++q) {
    asm volatile("" : "+a"(wr2[q]));
    asm volatile("" : "+a"(wz2[q]));
    asm volatile("" : "+a"(wn2[q]));
  }
  const float br = b_hh[j], bz = b_hh[j + 64], bn = b_hh[j + 128];

  hbuf[j] = 0.0f;
  float hj = 0.0f;
  __builtin_amdgcn_wave_barrier();

  const float* gp = GI + (size_t)b * NSn * G3n;
  float* hsp = hs + (size_t)b * NSn * GHn;

  // distance-4 prefetch ring (VGPRs are plentiful now)
  float pr[5], pz[5], pn[5];
#pragma unroll
  for (int u = 0; u < 4; ++u) {
    pr[u] = gp[(size_t)u * G3n + j];
    pz[u] = gp[(size_t)u * G3n + 64 + j];
    pn[u] = gp[(size_t)u * G3n + 128 + j];
  }

  for (int t = 0; t < NSn; ++t) {
    const size_t off = (size_t)min(t + 4, NSn - 1) * G3n;
    pr[4] = gp[off + j];
    pz[4] = gp[off + 64 + j];
    pn[4] = gp[off + 128 + j];

    const float4* h4p = (const float4*)hbuf;
    f2 ar[4], az[4], an[4];
#pragma unroll
    for (int u = 0; u < 4; ++u) { ar[u] = f2{0.f, 0.f}; az[u] = f2{0.f, 0.f}; an[u] = f2{0.f, 0.f}; }
#pragma unroll
    for (int q = 0; q < 16; ++q) {
      float4 h4 = h4p[q];                       // b128 broadcast read
      f2 hlo = {h4.x, h4.y};
      f2 hhi = {h4.z, h4.w};
      ar[(2 * q) % 4]     += wr2[2 * q] * hlo;
      ar[(2 * q + 1) % 4] += wr2[2 * q + 1] * hhi;
      az[(2 * q) % 4]     += wz2[2 * q] * hlo;
      az[(2 * q + 1) % 4] += wz2[2 * q + 1] * hhi;
      an[(2 * q) % 4]     += wn2[2 * q] * hlo;
      an[(2 * q + 1) % 4] += wn2[2 * q + 1] * hhi;
    }
    f2 sr2 = (ar[0] + ar[1]) + (ar[2] + ar[3]);
    f2 sz2 = (az[0] + az[1]) + (az[2] + az[3]);
    f2 sn2 = (an[0] + an[1]) + (an[2] + an[3]);

    float r = fsigmoid(pr[0] + br + sr2.x + sr2.y);
    float z = fsigmoid(pz[0] + bz + sz2.x + sz2.y);
    float n = ftanh_f(fmaf(r, bn + sn2.x + sn2.y, pn[0]));
    float hn = fmaf(z, hj - n, n);          // (1-z)*n + z*h

    // Pin ordering: reads of hbuf (above) before the write; write before
    // next iteration's reads. In-order per-wave DS pipe gives RAW safety.
    __builtin_amdgcn_wave_barrier();
    hbuf[j] = hn;
    __builtin_amdgcn_wave_barrier();
    hj = hn;
    hsp[(size_t)t * GHn + j] = hn;

#pragma unroll
    for (int u = 0; u < 4; ++u) { pr[u] = pr[u + 1]; pz[u] = pz[u + 1]; pn[u] = pn[u + 1]; }
  }
}

// ---------------------------------------------------------------------------
// Kernel 2b: cs[b, ts, i] = b_cs[i] + sum_k hs[b, ts, k] * W_cs[i, k]
// (unchanged)
// ---------------------------------------------------------------------------
__global__ __launch_bounds__(256) void cs_kernel(const float* __restrict__ hs,
                                                 const float* __restrict__ W_cs,
                                                 const float* __restrict__ b_cs,
                                                 float* __restrict__ cs) {
  __shared__ __align__(16) float WcT[64 * 36];  // [k][i] stride 36
  __shared__ __align__(16) float hsl[32 * 65];  // [t][k] stride 65
  __shared__ __align__(16) float bcs[32];
  const int tile = blockIdx.x;   // 0..31
  const int b    = blockIdx.y;
  const int t0   = tile * 32;
  const int nt   = min(32, NSn - t0);
  const int tid  = threadIdx.x;

  for (int e = tid; e < 32 * 64; e += 256) {
    int i = e >> 6, k = e & 63;
    WcT[k * 36 + i] = W_cs[e];
  }
  for (int e = tid; e < nt * 64; e += 256) {
    int t = e >> 6, k = e & 63;
    hsl[t * 65 + k] = hs[((size_t)b * NSn + t0 + t) * GHn + k];
  }
  if (tid < 32) bcs[tid] = b_cs[tid];
  __syncthreads();

  const int oq = tid & 7;    // output quad 0..7
  const int t  = tid >> 3;   // 0..31
  if (t < nt) {
    float4 acc = *(const float4*)&bcs[oq * 4];
    const float* hr = &hsl[t * 65];
#pragma unroll 4
    for (int k = 0; k < 64; ++k) {
      float hv = hr[k];
      float4 w = *(const float4*)&WcT[k * 36 + oq * 4];
      acc.x = fmaf(w.x, hv, acc.x);
      acc.y = fmaf(w.y, hv, acc.y);
      acc.z = fmaf(w.z, hv, acc.z);
      acc.w = fmaf(w.w, hv, acc.w);
    }
    *(float4*)&cs[((size_t)b * NSn + t0 + t) * 32 + oq * 4] = acc;
  }
}

// ---------------------------------------------------------------------------
// Kernel 3: fast MLP + overlap-add (unchanged)
// ---------------------------------------------------------------------------
__global__ __launch_bounds__(256) void out_kernel(const float* __restrict__ x,
                                                  const float* __restrict__ cs,
                                                  const float* __restrict__ W1,
                                                  const float* __restrict__ b1,
                                                  const float* __restrict__ W2,
                                                  const float* __restrict__ b2,
                                                  float* __restrict__ out) {
  __shared__ __align__(16) float A[33 * 65];     // [lf][k], k<32 = x, k>=32 = c
  __shared__ __align__(16) float W1T[64 * 68];   // [k][o] stride 68
  __shared__ __align__(16) float W2T[64 * 36];   // [k][o] stride 36
  __shared__ __align__(16) float h1loc[33 * 65]; // [lf][o] stride 65
  __shared__ __align__(16) float yloc[33 * 32];
  __shared__ __align__(16) float bb1[64];
  __shared__ __align__(16) float bb2[32];

  const int fb  = blockIdx.x;
  const int b   = blockIdx.y;
  const int f0  = fb * 32;
  const int nf  = min(33, NFn - f0);
  const int tid = threadIdx.x;

  for (int e = tid; e < 64 * 64; e += 256) {
    int o = e >> 6, k = e & 63;
    W1T[k * 68 + o] = W1[e];
  }
  for (int e = tid; e < 32 * 64; e += 256) {
    int o = e >> 6, k = e & 63;
    W2T[k * 36 + o] = W2[e];
  }
  if (tid < 64) bb1[tid] = b1[tid];
  if (tid < 32) bb2[tid] = b2[tid];

  for (int e = tid; e < 33 * 32; e += 256) {
    int lf = e >> 5, k = e & 31;
    int g = (f0 + lf) * 16 + k;
    A[lf * 65 + k] = (lf < nf && g < Tn) ? x[(size_t)b * Tn + g] : 0.0f;
  }
  for (int e = tid; e < 33 * 32; e += 256) {
    int lf = e >> 5, k = e & 31;
    int ts = max((f0 + lf) / 3 - 1, 0);
    A[lf * 65 + 32 + k] = (lf < nf) ? cs[((size_t)b * NSn + ts) * 32 + k] : 0.0f;
  }
  __syncthreads();

  // h1 = relu(W1 @ A + b1): item = (lf, oq), 4 outputs each
  for (int it = tid; it < 33 * 16; it += 256) {
    int lf = it >> 4, oq = it & 15;
    float4 acc = *(const float4*)&bb1[oq * 4];
    const float* ar = &A[lf * 65];
#pragma unroll 4
    for (int k = 0; k < 64; ++k) {
      float av = ar[k];
      float4 w = *(const float4*)&W1T[k * 68 + oq * 4];
      acc.x = fmaf(w.x, av, acc.x);
      acc.y = fmaf(w.y, av, acc.y);
      acc.z = fmaf(w.z, av, acc.z);
      acc.w = fmaf(w.w, av, acc.w);
    }
    acc.x = fmaxf(acc.x, 0.0f); acc.y = fmaxf(acc.y, 0.0f);
    acc.z = fmaxf(acc.z, 0.0f); acc.w = fmaxf(acc.w, 0.0f);
    *(float4*)&h1loc[lf * 65 + oq * 4] = acc;
  }
  __syncthreads();

  // y = W2 @ h1 + b2: item = (lf, oq), 4 outputs each
  for (int it = tid; it < 33 * 8; it += 256) {
    int lf = it >> 3, oq = it & 7;
    float4 acc = *(const float4*)&bb2[oq * 4];
    const float* hr = &h1loc[lf * 65];
#pragma unroll 4
    for (int k = 0; k < 64; ++k) {
      float hv = hr[k];
      float4 w = *(const float4*)&W2T[k * 36 + oq * 4];
      acc.x = fmaf(w.x, hv, acc.x);
      acc.y = fmaf(w.y, hv, acc.y);
      acc.z = fmaf(w.z, hv, acc.z);
      acc.w = fmaf(w.w, hv, acc.w);
    }
    *(float4*)&yloc[lf * 32 + oq * 4] = acc;
  }
  __syncthreads();

  // overlap-add: sample s gets y[f1][s%16] (if f1 valid) + y[f1-1][s%16+16]
  const int s0 = f0 * 16 + 16;
  const int s1 = min(s0 + 512, Tn);
  for (int s = s0 + tid; s < s1; s += 256) {
    int f1  = s >> 4;
    int o1  = s & 15;
    int lf1 = f1 - f0;                       // in [1, 32]
    float v = yloc[(lf1 - 1) * 32 + o1 + 16];
    if (lf1 < nf) v += yloc[lf1 * 32 + o1];
    out[(size_t)b * Tn + s] = v;
  }
  if (fb == 0 && tid < 16) out[(size_t)b * Tn + tid] = yloc[tid];
}

// ---------------------------------------------------------------------------
extern "C" void kernel_launch(void* const* d_in, const int* in_sizes, int n_in,
                              void* d_out, int out_size, void* d_ws, size_t ws_size,
                              hipStream_t stream) {
  const float* x    = (const float*)d_in[0];
  const float* W_ih = (const float*)d_in[1];
  const float* W_hh = (const float*)d_in[2];
  const float* b_ih = (const float*)d_in[3];
  const float* b_hh = (const float*)d_in[4];
  const float* W_cs = (const float*)d_in[5];
  const float* b_cs = (const float*)d_in[6];
  const float* W1   = (const float*)d_in[7];
  const float* b1   = (const float*)d_in[8];
  const float* W2   = (const float*)d_in[9];
  const float* b2   = (const float*)d_in[10];
  float* out = (float*)d_out;

  float* GI = (float*)d_ws;                        // 128*999*192 fp32 = 98.2MB
  float* hs = GI + (size_t)Bn * NSn * G3n;         // 128*999*64  fp32 = 32.7MB
  float* cs = GI;                                  // reuse GI (dead after gru)

  gi_kernel<<<dim3(32, Bn), 192, 0, stream>>>(x, W_ih, b_ih, GI);
  gru_kernel<<<Bn, 64, 0, stream>>>(GI, W_hh, b_hh, hs);
  cs_kernel<<<dim3(32, Bn), 256, 0, stream>>>(hs, W_cs, b_cs, cs);
  out_kernel<<<dim3(94, Bn), 256, 0, stream>>>(x, cs, W1, b1, W2, b2, out);
}

// Round 9
// 909.530 us; speedup vs baseline: 1.1915x; 1.1915x over previous
//
#include <hip/hip_runtime.h>

// Problem constants
constexpr int Bn  = 128;
constexpr int Tn  = 48000;
constexpr int NFn = 2999;   // fast frames
constexpr int NSn = 999;    // slow frames
constexpr int G3n = 192;    // 3*GH
constexpr int GHn = 64;

typedef float f2 __attribute__((ext_vector_type(2)));

// ---------------------------------------------------------------------------
// Kernel 1: GI[b, t, j] = b_ih[j] + sum_{k<96} x[b, t*48+k] * W_ih[j, k]
// (unchanged — known-good, no spills)
// ---------------------------------------------------------------------------
__global__ __launch_bounds__(192) void gi_kernel(const float* __restrict__ x,
                                                 const float* __restrict__ W_ih,
                                                 const float* __restrict__ b_ih,
                                                 float* __restrict__ GI) {
  __shared__ __align__(16) float WT[48 * 196];   // [k][j] padded stride 196
  __shared__ float xs[1584];                     // 31*48+96 samples
  const int tile = blockIdx.x;        // 0..31
  const int b    = blockIdx.y;        // 0..127
  const int t0   = tile * 32;
  const int nt   = min(32, NSn - t0); // 32 or 7 (last tile)
  const int tid  = threadIdx.x;

  const int span = (nt - 1) * 48 + 96;
  for (int i = tid; i < 1584; i += 192)
    xs[i] = (i < span) ? x[(size_t)b * Tn + t0 * 48 + i] : 0.0f;

  const int jq = tid % 48;   // j-quad index
  const int tg = tid / 48;   // t-group (0..3)
  const int j0 = jq * 4;

  float acc[8][4];
#pragma unroll
  for (int u = 0; u < 8; ++u)
#pragma unroll
    for (int jj = 0; jj < 4; ++jj) acc[u][jj] = b_ih[j0 + jj];

  for (int half = 0; half < 2; ++half) {
    __syncthreads();
    for (int e = tid; e < 192 * 48; e += 192) {
      int j = e / 48, k = e % 48;
      WT[k * 196 + j] = W_ih[j * 96 + half * 48 + k];
    }
    __syncthreads();
    for (int k = 0; k < 48; ++k) {
      float4 w = *(const float4*)&WT[k * 196 + j0];
#pragma unroll
      for (int u = 0; u < 8; ++u) {
        float xv = xs[(tg * 8 + u) * 48 + half * 48 + k];
        acc[u][0] = fmaf(xv, w.x, acc[u][0]);
        acc[u][1] = fmaf(xv, w.y, acc[u][1]);
        acc[u][2] = fmaf(xv, w.z, acc[u][2]);
        acc[u][3] = fmaf(xv, w.w, acc[u][3]);
      }
    }
  }

#pragma unroll
  for (int u = 0; u < 8; ++u) {
    int tl = tg * 8 + u;
    if (tl < nt) {
      float4 st = make_float4(acc[u][0], acc[u][1], acc[u][2], acc[u][3]);
      *(float4*)&GI[(size_t)(b * NSn + t0 + tl) * G3n + j0] = st;
    }
  }
}

// ---------------------------------------------------------------------------
// Kernel 2: GRU, one wave per batch element. Thread j owns gate rows
// (r_j, z_j, n_j) as f2 pairs (round-3 form — no asm/AGPR games, both
// proven harmful). THE ROUND-8 INSIGHT: vmcnt decrements in issue order,
// so the per-step global store of h forced every following GI-load wait to
// also wait for that store's HBM retirement (~500+ cyc) — the ~1170
// cyc/step invariant across rounds 3-8. Fix: h history accumulates in an
// LDS chunk buffer (37 steps/chunk); the step loop issues ZERO global
// stores. Flush to hs[] happens once per chunk (store-retire cost
// amortized 37x). Single wave => wave_barrier only, no s_barrier.
// ---------------------------------------------------------------------------
__device__ __forceinline__ float fsigmoid(float v) {
  return __fdividef(1.0f, 1.0f + __expf(-v));
}
__device__ __forceinline__ float ftanh_f(float v) {
  return 1.0f - __fdividef(2.0f, __expf(2.0f * v) + 1.0f);
}

__global__ __launch_bounds__(64, 1)
void gru_kernel(const float* __restrict__ GI,
                const float* __restrict__ W_hh,
                const float* __restrict__ b_hh,
                float* __restrict__ hs) {
  // row c = h before step c of the chunk; rows 1..37 = chunk's outputs
  __shared__ __align__(16) float hch[38 * 64];
  const int b = blockIdx.x;
  const int j = threadIdx.x;

  f2 wr2[32], wz2[32], wn2[32];
  const f2* Wr = (const f2*)(W_hh + (size_t)j * 64);
  const f2* Wz = (const f2*)(W_hh + (size_t)(j + 64) * 64);
  const f2* Wn = (const f2*)(W_hh + (size_t)(j + 128) * 64);
#pragma unroll
  for (int q = 0; q < 32; ++q) { wr2[q] = Wr[q]; wz2[q] = Wz[q]; wn2[q] = Wn[q]; }
  const float br = b_hh[j], bz = b_hh[j + 64], bn = b_hh[j + 128];

  hch[j] = 0.0f;                     // h_{-1} = 0 in row 0
  float hj = 0.0f;
  __builtin_amdgcn_wave_barrier();

  const float* gp = GI + (size_t)b * NSn * G3n;
  float* hsp = hs + (size_t)b * NSn * GHn;

  // distance-2 GI prefetch ring (loads only — no stores in the FIFO now)
  float pr0, pr1, pr2, pz0, pz1, pz2, pn0, pn1, pn2;
  pr0 = gp[0 * G3n + j];       pz0 = gp[0 * G3n + 64 + j];  pn0 = gp[0 * G3n + 128 + j];
  pr1 = gp[1 * G3n + j];       pz1 = gp[1 * G3n + 64 + j];  pn1 = gp[1 * G3n + 128 + j];

  for (int chunk = 0; chunk < 27; ++chunk) {    // 999 = 27 * 37
    const int t0 = chunk * 37;
    for (int c = 0; c < 37; ++c) {
      const int t = t0 + c;
      const size_t off = (size_t)min(t + 2, NSn - 1) * G3n;
      pr2 = gp[off + j];
      pz2 = gp[off + 64 + j];
      pn2 = gp[off + 128 + j];

      const f2* h2 = (const f2*)&hch[c * 64];
      f2 ar0 = {0.f, 0.f}, ar1 = {0.f, 0.f}, ar2 = {0.f, 0.f}, ar3 = {0.f, 0.f};
      f2 az0 = {0.f, 0.f}, az1 = {0.f, 0.f}, az2 = {0.f, 0.f}, az3 = {0.f, 0.f};
      f2 an0 = {0.f, 0.f}, an1 = {0.f, 0.f}, an2 = {0.f, 0.f}, an3 = {0.f, 0.f};
#pragma unroll
      for (int q = 0; q < 8; ++q) {
        f2 h0 = h2[q * 4 + 0], h1 = h2[q * 4 + 1], h2v = h2[q * 4 + 2], h3 = h2[q * 4 + 3];
        ar0 += wr2[q * 4 + 0] * h0; ar1 += wr2[q * 4 + 1] * h1;
        ar2 += wr2[q * 4 + 2] * h2v; ar3 += wr2[q * 4 + 3] * h3;
        az0 += wz2[q * 4 + 0] * h0; az1 += wz2[q * 4 + 1] * h1;
        az2 += wz2[q * 4 + 2] * h2v; az3 += wz2[q * 4 + 3] * h3;
        an0 += wn2[q * 4 + 0] * h0; an1 += wn2[q * 4 + 1] * h1;
        an2 += wn2[q * 4 + 2] * h2v; an3 += wn2[q * 4 + 3] * h3;
      }
      f2 sr = (ar0 + ar1) + (ar2 + ar3);
      f2 sz = (az0 + az1) + (az2 + az3);
      f2 sn = (an0 + an1) + (an2 + an3);

      float r = fsigmoid(pr0 + br + sr.x + sr.y);
      float z = fsigmoid(pz0 + bz + sz.x + sz.y);
      float n = ftanh_f(fmaf(r, bn + sn.x + sn.y, pn0));
      float hn = fmaf(z, hj - n, n);          // (1-z)*n + z*h

      // LDS only — no global store in the step loop.
      __builtin_amdgcn_wave_barrier();
      hch[(c + 1) * 64 + j] = hn;
      __builtin_amdgcn_wave_barrier();
      hj = hn;

      pr0 = pr1; pr1 = pr2;
      pz0 = pz1; pz1 = pz2;
      pn0 = pn1; pn1 = pn2;
    }

    // Burst-flush the chunk: rows 1..37 -> hs[t0 .. t0+36]. Coalesced
    // float4 stores; their retirement cost is paid once per 37 steps.
    for (int i = j; i < 37 * 16; i += 64) {
      int row = i >> 4, col = (i & 15) * 4;
      float4 v = *(const float4*)&hch[(row + 1) * 64 + col];
      *(float4*)&hsp[(size_t)(t0 + row) * GHn + col] = v;
    }
    __builtin_amdgcn_wave_barrier();
    hch[j] = hj;                      // next chunk's row 0 = last h
    __builtin_amdgcn_wave_barrier();
  }
}

// ---------------------------------------------------------------------------
// Kernel 2b: cs[b, ts, i] = b_cs[i] + sum_k hs[b, ts, k] * W_cs[i, k]
// (unchanged)
// ---------------------------------------------------------------------------
__global__ __launch_bounds__(256) void cs_kernel(const float* __restrict__ hs,
                                                 const float* __restrict__ W_cs,
                                                 const float* __restrict__ b_cs,
                                                 float* __restrict__ cs) {
  __shared__ __align__(16) float WcT[64 * 36];  // [k][i] stride 36
  __shared__ __align__(16) float hsl[32 * 65];  // [t][k] stride 65
  __shared__ __align__(16) float bcs[32];
  const int tile = blockIdx.x;   // 0..31
  const int b    = blockIdx.y;
  const int t0   = tile * 32;
  const int nt   = min(32, NSn - t0);
  const int tid  = threadIdx.x;

  for (int e = tid; e < 32 * 64; e += 256) {
    int i = e >> 6, k = e & 63;
    WcT[k * 36 + i] = W_cs[e];
  }
  for (int e = tid; e < nt * 64; e += 256) {
    int t = e >> 6, k = e & 63;
    hsl[t * 65 + k] = hs[((size_t)b * NSn + t0 + t) * GHn + k];
  }
  if (tid < 32) bcs[tid] = b_cs[tid];
  __syncthreads();

  const int oq = tid & 7;    // output quad 0..7
  const int t  = tid >> 3;   // 0..31
  if (t < nt) {
    float4 acc = *(const float4*)&bcs[oq * 4];
    const float* hr = &hsl[t * 65];
#pragma unroll 4
    for (int k = 0; k < 64; ++k) {
      float hv = hr[k];
      float4 w = *(const float4*)&WcT[k * 36 + oq * 4];
      acc.x = fmaf(w.x, hv, acc.x);
      acc.y = fmaf(w.y, hv, acc.y);
      acc.z = fmaf(w.z, hv, acc.z);
      acc.w = fmaf(w.w, hv, acc.w);
    }
    *(float4*)&cs[((size_t)b * NSn + t0 + t) * 32 + oq * 4] = acc;
  }
}

// ---------------------------------------------------------------------------
// Kernel 3: fast MLP + overlap-add (unchanged)
// ---------------------------------------------------------------------------
__global__ __launch_bounds__(256) void out_kernel(const float* __restrict__ x,
                                                  const float* __restrict__ cs,
                                                  const float* __restrict__ W1,
                                                  const float* __restrict__ b1,
                                                  const float* __restrict__ W2,
                                                  const float* __restrict__ b2,
                                                  float* __restrict__ out) {
  __shared__ __align__(16) float A[33 * 65];     // [lf][k], k<32 = x, k>=32 = c
  __shared__ __align__(16) float W1T[64 * 68];   // [k][o] stride 68
  __shared__ __align__(16) float W2T[64 * 36];   // [k][o] stride 36
  __shared__ __align__(16) float h1loc[33 * 65]; // [lf][o] stride 65
  __shared__ __align__(16) float yloc[33 * 32];
  __shared__ __align__(16) float bb1[64];
  __shared__ __align__(16) float bb2[32];

  const int fb  = blockIdx.x;
  const int b   = blockIdx.y;
  const int f0  = fb * 32;
  const int nf  = min(33, NFn - f0);
  const int tid = threadIdx.x;

  for (int e = tid; e < 64 * 64; e += 256) {
    int o = e >> 6, k = e & 63;
    W1T[k * 68 + o] = W1[e];
  }
  for (int e = tid; e < 32 * 64; e += 256) {
    int o = e >> 6, k = e & 63;
    W2T[k * 36 + o] = W2[e];
  }
  if (tid < 64) bb1[tid] = b1[tid];
  if (tid < 32) bb2[tid] = b2[tid];

  for (int e = tid; e < 33 * 32; e += 256) {
    int lf = e >> 5, k = e & 31;
    int g = (f0 + lf) * 16 + k;
    A[lf * 65 + k] = (lf < nf && g < Tn) ? x[(size_t)b * Tn + g] : 0.0f;
  }
  for (int e = tid; e < 33 * 32; e += 256) {
    int lf = e >> 5, k = e & 31;
    int ts = max((f0 + lf) / 3 - 1, 0);
    A[lf * 65 + 32 + k] = (lf < nf) ? cs[((size_t)b * NSn + ts) * 32 + k] : 0.0f;
  }
  __syncthreads();

  // h1 = relu(W1 @ A + b1): item = (lf, oq), 4 outputs each
  for (int it = tid; it < 33 * 16; it += 256) {
    int lf = it >> 4, oq = it & 15;
    float4 acc = *(const float4*)&bb1[oq * 4];
    const float* ar = &A[lf * 65];
#pragma unroll 4
    for (int k = 0; k < 64; ++k) {
      float av = ar[k];
      float4 w = *(const float4*)&W1T[k * 68 + oq * 4];
      acc.x = fmaf(w.x, av, acc.x);
      acc.y = fmaf(w.y, av, acc.y);
      acc.z = fmaf(w.z, av, acc.z);
      acc.w = fmaf(w.w, av, acc.w);
    }
    acc.x = fmaxf(acc.x, 0.0f); acc.y = fmaxf(acc.y, 0.0f);
    acc.z = fmaxf(acc.z, 0.0f); acc.w = fmaxf(acc.w, 0.0f);
    *(float4*)&h1loc[lf * 65 + oq * 4] = acc;
  }
  __syncthreads();

  // y = W2 @ h1 + b2: item = (lf, oq), 4 outputs each
  for (int it = tid; it < 33 * 8; it += 256) {
    int lf = it >> 3, oq = it & 7;
    float4 acc = *(const float4*)&bb2[oq * 4];
    const float* hr = &h1loc[lf * 65];
#pragma unroll 4
    for (int k = 0; k < 64; ++k) {
      float hv = hr[k];
      float4 w = *(const float4*)&W2T[k * 36 + oq * 4];
      acc.x = fmaf(w.x, hv, acc.x);
      acc.y = fmaf(w.y, hv, acc.y);
      acc.z = fmaf(w.z, hv, acc.z);
      acc.w = fmaf(w.w, hv, acc.w);
    }
    *(float4*)&yloc[lf * 32 + oq * 4] = acc;
  }
  __syncthreads();

  // overlap-add: sample s gets y[f1][s%16] (if f1 valid) + y[f1-1][s%16+16]
  const int s0 = f0 * 16 + 16;
  const int s1 = min(s0 + 512, Tn);
  for (int s = s0 + tid; s < s1; s += 256) {
    int f1  = s >> 4;
    int o1  = s & 15;
    int lf1 = f1 - f0;                       // in [1, 32]
    float v = yloc[(lf1 - 1) * 32 + o1 + 16];
    if (lf1 < nf) v += yloc[lf1 * 32 + o1];
    out[(size_t)b * Tn + s] = v;
  }
  if (fb == 0 && tid < 16) out[(size_t)b * Tn + tid] = yloc[tid];
}

// ---------------------------------------------------------------------------
extern "C" void kernel_launch(void* const* d_in, const int* in_sizes, int n_in,
                              void* d_out, int out_size, void* d_ws, size_t ws_size,
                              hipStream_t stream) {
  const float* x    = (const float*)d_in[0];
  const float* W_ih = (const float*)d_in[1];
  const float* W_hh = (const float*)d_in[2];
  const float* b_ih = (const float*)d_in[3];
  const float* b_hh = (const float*)d_in[4];
  const float* W_cs = (const float*)d_in[5];
  const float* b_cs = (const float*)d_in[6];
  const float* W1   = (const float*)d_in[7];
  const float* b1   = (const float*)d_in[8];
  const float* W2   = (const float*)d_in[9];
  const float* b2   = (const float*)d_in[10];
  float* out = (float*)d_out;

  float* GI = (float*)d_ws;                        // 128*999*192 fp32 = 98.2MB
  float* hs = GI + (size_t)Bn * NSn * G3n;         // 128*999*64  fp32 = 32.7MB
  float* cs = GI;                                  // reuse GI (dead after gru)

  gi_kernel<<<dim3(32, Bn), 192, 0, stream>>>(x, W_ih, b_ih, GI);
  gru_kernel<<<Bn, 64, 0, stream>>>(GI, W_hh, b_hh, hs);
  cs_kernel<<<dim3(32, Bn), 256, 0, stream>>>(hs, W_cs, b_cs, cs);
  out_kernel<<<dim3(94, Bn), 256, 0, stream>>>(x, cs, W1, b1, W2, b2, out);
}

// Round 10
// 887.386 us; speedup vs baseline: 1.2212x; 1.0250x over previous
//
#include <hip/hip_runtime.h>

// Problem constants
constexpr int Bn  = 128;
constexpr int Tn  = 48000;
constexpr int NFn = 2999;   // fast frames
constexpr int NSn = 999;    // slow frames
constexpr int G3n = 192;    // 3*GH
constexpr int GHn = 64;

typedef float f2 __attribute__((ext_vector_type(2)));

// ---------------------------------------------------------------------------
// Kernel 1: GI[b, t, j] = b_ih[j] + sum_{k<96} x[b, t*48+k] * W_ih[j, k]
// (unchanged — known-good, no spills)
// ---------------------------------------------------------------------------
__global__ __launch_bounds__(192) void gi_kernel(const float* __restrict__ x,
                                                 const float* __restrict__ W_ih,
                                                 const float* __restrict__ b_ih,
                                                 float* __restrict__ GI) {
  __shared__ __align__(16) float WT[48 * 196];   // [k][j] padded stride 196
  __shared__ float xs[1584];                     // 31*48+96 samples
  const int tile = blockIdx.x;        // 0..31
  const int b    = blockIdx.y;        // 0..127
  const int t0   = tile * 32;
  const int nt   = min(32, NSn - t0); // 32 or 7 (last tile)
  const int tid  = threadIdx.x;

  const int span = (nt - 1) * 48 + 96;
  for (int i = tid; i < 1584; i += 192)
    xs[i] = (i < span) ? x[(size_t)b * Tn + t0 * 48 + i] : 0.0f;

  const int jq = tid % 48;   // j-quad index
  const int tg = tid / 48;   // t-group (0..3)
  const int j0 = jq * 4;

  float acc[8][4];
#pragma unroll
  for (int u = 0; u < 8; ++u)
#pragma unroll
    for (int jj = 0; jj < 4; ++jj) acc[u][jj] = b_ih[j0 + jj];

  for (int half = 0; half < 2; ++half) {
    __syncthreads();
    for (int e = tid; e < 192 * 48; e += 192) {
      int j = e / 48, k = e % 48;
      WT[k * 196 + j] = W_ih[j * 96 + half * 48 + k];
    }
    __syncthreads();
    for (int k = 0; k < 48; ++k) {
      float4 w = *(const float4*)&WT[k * 196 + j0];
#pragma unroll
      for (int u = 0; u < 8; ++u) {
        float xv = xs[(tg * 8 + u) * 48 + half * 48 + k];
        acc[u][0] = fmaf(xv, w.x, acc[u][0]);
        acc[u][1] = fmaf(xv, w.y, acc[u][1]);
        acc[u][2] = fmaf(xv, w.z, acc[u][2]);
        acc[u][3] = fmaf(xv, w.w, acc[u][3]);
      }
    }
  }

#pragma unroll
  for (int u = 0; u < 8; ++u) {
    int tl = tg * 8 + u;
    if (tl < nt) {
      float4 st = make_float4(acc[u][0], acc[u][1], acc[u][2], acc[u][3]);
      *(float4*)&GI[(size_t)(b * NSn + t0 + tl) * G3n + j0] = st;
    }
  }
}

// ---------------------------------------------------------------------------
// Kernel 2: GRU — 3-wave gate-split. 192 threads/block, one block per batch.
// Thread tid owns gate row tid: 64 weight floats = 32 f2 regs -> ~100 VGPRs
// total, UNDER the allocator's ~128 cap, so weights stay resident with no
// per-step reload (rounds 1-9: 192 floats/lane could never be resident and
// cost ~48KB L1 traffic/step = the ~1200 cyc/step invariant).
// Per-step cross-wave combine uses s_barrier; the barrier's vmcnt(0) drain
// is free because the step loop issues ZERO global ops: GI is burst-loaded
// to LDS per 32-step chunk, h history burst-flushed per chunk.
// ---------------------------------------------------------------------------
__device__ __forceinline__ float fsigmoid(float v) {
  return __fdividef(1.0f, 1.0f + __expf(-v));
}
__device__ __forceinline__ float ftanh_f(float v) {
  return 1.0f - __fdividef(2.0f, __expf(2.0f * v) + 1.0f);
}

__global__ __launch_bounds__(192, 1)
void gru_kernel(const float* __restrict__ GI,
                const float* __restrict__ W_hh,
                const float* __restrict__ b_hh,
                float* __restrict__ hs) {
  __shared__ __align__(16) float gic[32 * 192];   // GI chunk [c][j]
  __shared__ __align__(16) float hch[33 * 64];    // h history; row c = h before step c
  __shared__ float gates[192];                    // h-dot (+bias) per gate row
  const int b   = blockIdx.x;
  const int tid = threadIdx.x;

  f2 w[32];
  const f2* Wp = (const f2*)(W_hh + (size_t)tid * 64);
#pragma unroll
  for (int q = 0; q < 32; ++q) w[q] = Wp[q];
  const float bias = b_hh[tid];

  if (tid < 64) hch[tid] = 0.0f;
  float hj = 0.0f;                                // wave-0 lanes: current h_j

  const float* gp  = GI + (size_t)b * NSn * G3n;
  float* hsp       = hs + (size_t)b * NSn * GHn;

  for (int t0 = 0; t0 < NSn; t0 += 32) {
    const int nc = min(32, NSn - t0);

    // burst-load GI chunk (nc*192 floats, coalesced float4)
    {
      const float4* src = (const float4*)(gp + (size_t)t0 * G3n);
      float4* dst = (float4*)gic;
      for (int i = tid; i < nc * 48; i += 192) dst[i] = src[i];
    }
    __syncthreads();   // drains the chunk's loads+prior stores ONCE per chunk

    for (int c = 0; c < nc; ++c) {
      // h-dot: 16 broadcast b128 reads + 32 pk_fma per thread
      const float4* h4 = (const float4*)&hch[c * 64];
      f2 a0 = {0.f, 0.f}, a1 = {0.f, 0.f}, a2 = {0.f, 0.f}, a3 = {0.f, 0.f};
#pragma unroll
      for (int q = 0; q < 8; ++q) {
        float4 hA = h4[2 * q];
        float4 hB = h4[2 * q + 1];
        a0 += w[4 * q + 0] * f2{hA.x, hA.y};
        a1 += w[4 * q + 1] * f2{hA.z, hA.w};
        a2 += w[4 * q + 2] * f2{hB.x, hB.y};
        a3 += w[4 * q + 3] * f2{hB.z, hB.w};
      }
      f2 s = (a0 + a1) + (a2 + a3);
      gates[tid] = bias + s.x + s.y;
      __syncthreads();                 // nothing outstanding -> cheap

      if (tid < 64) {                  // wave 0: gating + h update
        float gr = gic[c * 192 + tid];
        float gz = gic[c * 192 + 64 + tid];
        float gn = gic[c * 192 + 128 + tid];
        float r  = fsigmoid(gr + gates[tid]);
        float z  = fsigmoid(gz + gates[tid + 64]);
        float n  = ftanh_f(fmaf(r, gates[tid + 128], gn));
        float hn = fmaf(z, hj - n, n);      // (1-z)*n + z*h
        hj = hn;
        hch[(c + 1) * 64 + tid] = hn;
      }
      __syncthreads();                 // publish h_{t+1}; cheap
    }

    // burst-flush h rows 1..nc -> hs[t0 .. t0+nc) (coalesced float4)
    for (int i = tid; i < nc * 16; i += 192) {
      int row = i >> 4, col = (i & 15) * 4;
      *(float4*)&hsp[(size_t)(t0 + row) * GHn + col] =
          *(const float4*)&hch[(row + 1) * 64 + col];
    }
    if (tid < 64) hch[tid] = hj;       // carry: next chunk's row 0
    // next iteration's post-load __syncthreads orders flush/carry vs reads
  }
}

// ---------------------------------------------------------------------------
// Kernel 2b: cs[b, ts, i] = b_cs[i] + sum_k hs[b, ts, k] * W_cs[i, k]
// (unchanged)
// ---------------------------------------------------------------------------
__global__ __launch_bounds__(256) void cs_kernel(const float* __restrict__ hs,
                                                 const float* __restrict__ W_cs,
                                                 const float* __restrict__ b_cs,
                                                 float* __restrict__ cs) {
  __shared__ __align__(16) float WcT[64 * 36];  // [k][i] stride 36
  __shared__ __align__(16) float hsl[32 * 65];  // [t][k] stride 65
  __shared__ __align__(16) float bcs[32];
  const int tile = blockIdx.x;   // 0..31
  const int b    = blockIdx.y;
  const int t0   = tile * 32;
  const int nt   = min(32, NSn - t0);
  const int tid  = threadIdx.x;

  for (int e = tid; e < 32 * 64; e += 256) {
    int i = e >> 6, k = e & 63;
    WcT[k * 36 + i] = W_cs[e];
  }
  for (int e = tid; e < nt * 64; e += 256) {
    int t = e >> 6, k = e & 63;
    hsl[t * 65 + k] = hs[((size_t)b * NSn + t0 + t) * GHn + k];
  }
  if (tid < 32) bcs[tid] = b_cs[tid];
  __syncthreads();

  const int oq = tid & 7;    // output quad 0..7
  const int t  = tid >> 3;   // 0..31
  if (t < nt) {
    float4 acc = *(const float4*)&bcs[oq * 4];
    const float* hr = &hsl[t * 65];
#pragma unroll 4
    for (int k = 0; k < 64; ++k) {
      float hv = hr[k];
      float4 w = *(const float4*)&WcT[k * 36 + oq * 4];
      acc.x = fmaf(w.x, hv, acc.x);
      acc.y = fmaf(w.y, hv, acc.y);
      acc.z = fmaf(w.z, hv, acc.z);
      acc.w = fmaf(w.w, hv, acc.w);
    }
    *(float4*)&cs[((size_t)b * NSn + t0 + t) * 32 + oq * 4] = acc;
  }
}

// ---------------------------------------------------------------------------
// Kernel 3: fast MLP + overlap-add (unchanged)
// ---------------------------------------------------------------------------
__global__ __launch_bounds__(256) void out_kernel(const float* __restrict__ x,
                                                  const float* __restrict__ cs,
                                                  const float* __restrict__ W1,
                                                  const float* __restrict__ b1,
                                                  const float* __restrict__ W2,
                                                  const float* __restrict__ b2,
                                                  float* __restrict__ out) {
  __shared__ __align__(16) float A[33 * 65];     // [lf][k], k<32 = x, k>=32 = c
  __shared__ __align__(16) float W1T[64 * 68];   // [k][o] stride 68
  __shared__ __align__(16) float W2T[64 * 36];   // [k][o] stride 36
  __shared__ __align__(16) float h1loc[33 * 65]; // [lf][o] stride 65
  __shared__ __align__(16) float yloc[33 * 32];
  __shared__ __align__(16) float bb1[64];
  __shared__ __align__(16) float bb2[32];

  const int fb  = blockIdx.x;
  const int b   = blockIdx.y;
  const int f0  = fb * 32;
  const int nf  = min(33, NFn - f0);
  const int tid = threadIdx.x;

  for (int e = tid; e < 64 * 64; e += 256) {
    int o = e >> 6, k = e & 63;
    W1T[k * 68 + o] = W1[e];
  }
  for (int e = tid; e < 32 * 64; e += 256) {
    int o = e >> 6, k = e & 63;
    W2T[k * 36 + o] = W2[e];
  }
  if (tid < 64) bb1[tid] = b1[tid];
  if (tid < 32) bb2[tid] = b2[tid];

  for (int e = tid; e < 33 * 32; e += 256) {
    int lf = e >> 5, k = e & 31;
    int g = (f0 + lf) * 16 + k;
    A[lf * 65 + k] = (lf < nf && g < Tn) ? x[(size_t)b * Tn + g] : 0.0f;
  }
  for (int e = tid; e < 33 * 32; e += 256) {
    int lf = e >> 5, k = e & 31;
    int ts = max((f0 + lf) / 3 - 1, 0);
    A[lf * 65 + 32 + k] = (lf < nf) ? cs[((size_t)b * NSn + ts) * 32 + k] : 0.0f;
  }
  __syncthreads();

  // h1 = relu(W1 @ A + b1): item = (lf, oq), 4 outputs each
  for (int it = tid; it < 33 * 16; it += 256) {
    int lf = it >> 4, oq = it & 15;
    float4 acc = *(const float4*)&bb1[oq * 4];
    const float* ar = &A[lf * 65];
#pragma unroll 4
    for (int k = 0; k < 64; ++k) {
      float av = ar[k];
      float4 w = *(const float4*)&W1T[k * 68 + oq * 4];
      acc.x = fmaf(w.x, av, acc.x);
      acc.y = fmaf(w.y, av, acc.y);
      acc.z = fmaf(w.z, av, acc.z);
      acc.w = fmaf(w.w, av, acc.w);
    }
    acc.x = fmaxf(acc.x, 0.0f); acc.y = fmaxf(acc.y, 0.0f);
    acc.z = fmaxf(acc.z, 0.0f); acc.w = fmaxf(acc.w, 0.0f);
    *(float4*)&h1loc[lf * 65 + oq * 4] = acc;
  }
  __syncthreads();

  // y = W2 @ h1 + b2: item = (lf, oq), 4 outputs each
  for (int it = tid; it < 33 * 8; it += 256) {
    int lf = it >> 3, oq = it & 7;
    float4 acc = *(const float4*)&bb2[oq * 4];
    const float* hr = &h1loc[lf * 65];
#pragma unroll 4
    for (int k = 0; k < 64; ++k) {
      float hv = hr[k];
      float4 w = *(const float4*)&W2T[k * 36 + oq * 4];
      acc.x = fmaf(w.x, hv, acc.x);
      acc.y = fmaf(w.y, hv, acc.y);
      acc.z = fmaf(w.z, hv, acc.z);
      acc.w = fmaf(w.w, hv, acc.w);
    }
    *(float4*)&yloc[lf * 32 + oq * 4] = acc;
  }
  __syncthreads();

  // overlap-add: sample s gets y[f1][s%16] (if f1 valid) + y[f1-1][s%16+16]
  const int s0 = f0 * 16 + 16;
  const int s1 = min(s0 + 512, Tn);
  for (int s = s0 + tid; s < s1; s += 256) {
    int f1  = s >> 4;
    int o1  = s & 15;
    int lf1 = f1 - f0;                       // in [1, 32]
    float v = yloc[(lf1 - 1) * 32 + o1 + 16];
    if (lf1 < nf) v += yloc[lf1 * 32 + o1];
    out[(size_t)b * Tn + s] = v;
  }
  if (fb == 0 && tid < 16) out[(size_t)b * Tn + tid] = yloc[tid];
}

// ---------------------------------------------------------------------------
extern "C" void kernel_launch(void* const* d_in, const int* in_sizes, int n_in,
                              void* d_out, int out_size, void* d_ws, size_t ws_size,
                              hipStream_t stream) {
  const float* x    = (const float*)d_in[0];
  const float* W_ih = (const float*)d_in[1];
  const float* W_hh = (const float*)d_in[2];
  const float* b_ih = (const float*)d_in[3];
  const float* b_hh = (const float*)d_in[4];
  const float* W_cs = (const float*)d_in[5];
  const float* b_cs = (const float*)d_in[6];
  const float* W1   = (const float*)d_in[7];
  const float* b1   = (const float*)d_in[8];
  const float* W2   = (const float*)d_in[9];
  const float* b2   = (const float*)d_in[10];
  float* out = (float*)d_out;

  float* GI = (float*)d_ws;                        // 128*999*192 fp32 = 98.2MB
  float* hs = GI + (size_t)Bn * NSn * G3n;         // 128*999*64  fp32 = 32.7MB
  float* cs = GI;                                  // reuse GI (dead after gru)

  gi_kernel<<<dim3(32, Bn), 192, 0, stream>>>(x, W_ih, b_ih, GI);
  gru_kernel<<<Bn, 192, 0, stream>>>(GI, W_hh, b_hh, hs);
  cs_kernel<<<dim3(32, Bn), 256, 0, stream>>>(hs, W_cs, b_cs, cs);
  out_kernel<<<dim3(94, Bn), 256, 0, stream>>>(x, cs, W1, b1, W2, b2, out);
}